// Round 1
// baseline (404.223 us; speedup 1.0000x reference)
//
#include <hip/hip_runtime.h>
#include <hip/hip_bf16.h>

// Problem dims (fixed by setup_inputs): B=2,S=2048 -> T=4096 tokens, D=1024, H=2048, E=8, top_k=2
#define TOK 4096
#define DD 1024
#define HH 2048
#define NE 8
#define RTOT (TOK * 2)   // total (token,expert) rows = 8192

typedef __attribute__((ext_vector_type(8))) short bf16x8;
typedef __attribute__((ext_vector_type(4))) float f32x4;

// fp32 -> bf16 round-to-nearest-even
static __device__ __forceinline__ unsigned short f2bf(float f) {
  union { float f; unsigned int u; } v; v.f = f;
  unsigned int r = v.u + 0x7fffu + ((v.u >> 16) & 1u);
  return (unsigned short)(r >> 16);
}

// ---------------- router: fp32 gate scores, top-2, softmax over top-2 ----------------
__global__ void router_k(const float* __restrict__ x, const float* __restrict__ gw,
                         int* __restrict__ topi, float* __restrict__ topp,
                         int* __restrict__ counts) {
  const int lane = threadIdx.x & 63;
  const int t = blockIdx.x * 4 + (threadIdx.x >> 6);
  const float4* xr = (const float4*)(x + (size_t)t * DD);
  float acc[NE];
#pragma unroll
  for (int e = 0; e < NE; ++e) acc[e] = 0.f;
#pragma unroll
  for (int i = 0; i < 4; ++i) {
    const float4 xv = xr[i * 64 + lane];
#pragma unroll
    for (int e = 0; e < NE; ++e) {
      const float4 gv = ((const float4*)(gw + (size_t)e * DD))[i * 64 + lane];
      acc[e] += xv.x * gv.x + xv.y * gv.y + xv.z * gv.z + xv.w * gv.w;
    }
  }
#pragma unroll
  for (int e = 0; e < NE; ++e)
#pragma unroll
    for (int s = 32; s > 0; s >>= 1) acc[e] += __shfl_xor(acc[e], s, 64);
  if (lane == 0) {
    int i0 = 0; float v0 = acc[0];
#pragma unroll
    for (int e = 1; e < NE; ++e) if (acc[e] > v0) { v0 = acc[e]; i0 = e; }   // ties -> lowest idx (matches top_k)
    int i1 = -1; float v1 = -1e30f;
#pragma unroll
    for (int e = 0; e < NE; ++e) if (e != i0 && acc[e] > v1) { v1 = acc[e]; i1 = e; }
    const float ex = __expf(v1 - v0);
    const float inv = 1.f / (1.f + ex);
    topi[t * 2] = i0; topi[t * 2 + 1] = i1;
    topp[t * 2] = inv; topp[t * 2 + 1] = ex * inv;
    atomicAdd(&counts[i0], 1); atomicAdd(&counts[i1], 1);
  }
}

// ---------------- x fp32 -> bf16 ----------------
__global__ void convert_k(const float* __restrict__ x, unsigned short* __restrict__ xb) {
  const int i = blockIdx.x * 256 + threadIdx.x;       // TOK*DD/4 threads
  const float4 v = ((const float4*)x)[i];
  ushort4 o;
  o.x = f2bf(v.x); o.y = f2bf(v.y); o.z = f2bf(v.z); o.w = f2bf(v.w);
  ((ushort4*)xb)[i] = o;
}

// ---------------- tiny exclusive scan over 8 counts ----------------
__global__ void scan_k(const int* __restrict__ counts, int* __restrict__ offsets,
                       int* __restrict__ cursor) {
  if (threadIdx.x == 0) {
    int s = 0;
    for (int e = 0; e < NE; ++e) { offsets[e] = s; cursor[e] = s; s += counts[e]; }
  }
}

// ---------------- scatter tokens into per-expert row lists ----------------
__global__ void scatter_k(const int* __restrict__ topi, const float* __restrict__ topp,
                          int* __restrict__ cursor, int* __restrict__ perm,
                          float* __restrict__ prow, int* __restrict__ rowid) {
  const int t = blockIdx.x * 256 + threadIdx.x;
#pragma unroll
  for (int k = 0; k < 2; ++k) {
    const int e = topi[t * 2 + k];
    const int pos = atomicAdd(&cursor[e], 1);
    perm[pos] = t;
    prow[pos] = topp[t * 2 + k];
    rowid[t * 2 + k] = pos;
  }
}

// ---------------- GEMM1: gathered X @ (w1,w2) -> h = silu(g)*u (bf16) ----------------
// tile: BM=128, BN=64 (per output), BK=32; 4 waves, each 64x32 of both g and u.
__global__ __launch_bounds__(256) void gemm1_k(
    const unsigned short* __restrict__ Xb, const float* __restrict__ w1,
    const float* __restrict__ w2, const int* __restrict__ counts,
    const int* __restrict__ offsets, const int* __restrict__ perm,
    unsigned short* __restrict__ hbuf) {
  const int e = blockIdx.z;
  const int ne = counts[e];
  const int m0 = blockIdx.y * 128;
  if (m0 >= ne) return;
  const int off = offsets[e];
  const int n0 = blockIdx.x * 64;

  __shared__ unsigned short xs[128 * 40];   // [row][k] stride 40 (80B, 2-way bank max)
  __shared__ unsigned short w1s[64 * 40];   // [n][k]
  __shared__ unsigned short w2s[64 * 40];

  const int tid = threadIdx.x;
  // X staging: thread -> (row, 16B-seg)
  const int xrow0 = tid >> 2, xseg = tid & 3;
  const int ra = min(m0 + xrow0, ne - 1);
  const int rb = min(m0 + xrow0 + 64, ne - 1);
  const uint4* xpa = (const uint4*)(Xb + (size_t)perm[off + ra] * DD);
  const uint4* xpb = (const uint4*)(Xb + (size_t)perm[off + rb] * DD);
  // W staging: thread -> (n, k-chunk of 8); column loads, coalesced across lanes
  const int wn_ = tid & 63, wkc = (tid >> 6) * 8;
  const float* w1p = w1 + (size_t)e * DD * HH + n0 + wn_;
  const float* w2p = w2 + (size_t)e * DD * HH + n0 + wn_;

  const int lane = tid & 63, wv = tid >> 6;
  const int wm = (wv >> 1) * 64, wn = (wv & 1) * 32;
  const int lr = lane & 15, lkb = (lane >> 4) * 8;

  f32x4 accG[4][2], accU[4][2];
#pragma unroll
  for (int a = 0; a < 4; ++a)
#pragma unroll
    for (int b = 0; b < 2; ++b) {
      accG[a][b] = f32x4{0.f, 0.f, 0.f, 0.f};
      accU[a][b] = f32x4{0.f, 0.f, 0.f, 0.f};
    }

  for (int it = 0; it < DD / 32; ++it) {
    const int k0 = it * 32;
    const uint4 va = xpa[it * 4 + xseg];
    const uint4 vb = xpb[it * 4 + xseg];
    union { unsigned short u[8]; uint4 v; } p1, p2;
#pragma unroll
    for (int j = 0; j < 8; ++j) {
      p1.u[j] = f2bf(w1p[(size_t)(k0 + wkc + j) * HH]);
      p2.u[j] = f2bf(w2p[(size_t)(k0 + wkc + j) * HH]);
    }
    __syncthreads();
    *(uint4*)&xs[xrow0 * 40 + xseg * 8] = va;
    *(uint4*)&xs[(xrow0 + 64) * 40 + xseg * 8] = vb;
    *(uint4*)&w1s[wn_ * 40 + wkc] = p1.v;
    *(uint4*)&w2s[wn_ * 40 + wkc] = p2.v;
    __syncthreads();
    bf16x8 af[4], b1[2], b2[2];
#pragma unroll
    for (int mf = 0; mf < 4; ++mf)
      af[mf] = *(const bf16x8*)&xs[(wm + mf * 16 + lr) * 40 + lkb];
#pragma unroll
    for (int nf = 0; nf < 2; ++nf) {
      b1[nf] = *(const bf16x8*)&w1s[(wn + nf * 16 + lr) * 40 + lkb];
      b2[nf] = *(const bf16x8*)&w2s[(wn + nf * 16 + lr) * 40 + lkb];
    }
#pragma unroll
    for (int mf = 0; mf < 4; ++mf)
#pragma unroll
      for (int nf = 0; nf < 2; ++nf) {
        accG[mf][nf] = __builtin_amdgcn_mfma_f32_16x16x32_bf16(af[mf], b1[nf], accG[mf][nf], 0, 0, 0);
        accU[mf][nf] = __builtin_amdgcn_mfma_f32_16x16x32_bf16(af[mf], b2[nf], accU[mf][nf], 0, 0, 0);
      }
  }
#pragma unroll
  for (int mf = 0; mf < 4; ++mf)
#pragma unroll
    for (int nf = 0; nf < 2; ++nf)
#pragma unroll
      for (int r = 0; r < 4; ++r) {
        const int rl = m0 + wm + mf * 16 + (lane >> 4) * 4 + r;
        if (rl < ne) {
          const int col = n0 + wn + nf * 16 + lr;
          const float g = accG[mf][nf][r], u = accU[mf][nf][r];
          const float hv = g / (1.f + __expf(-g)) * u;   // silu(g)*u
          hbuf[(size_t)(off + rl) * HH + col] = f2bf(hv);
        }
      }
}

// ---------------- GEMM2: h @ w3, scaled by routing prob -> y (fp32) ----------------
__global__ __launch_bounds__(256) void gemm2_k(
    const unsigned short* __restrict__ hbuf, const float* __restrict__ w3,
    const int* __restrict__ counts, const int* __restrict__ offsets,
    const float* __restrict__ prow, float* __restrict__ ybuf) {
  const int e = blockIdx.z;
  const int ne = counts[e];
  const int m0 = blockIdx.y * 128;
  if (m0 >= ne) return;
  const int off = offsets[e];
  const int n0 = blockIdx.x * 64;

  __shared__ unsigned short hs[128 * 40];
  __shared__ unsigned short w3s[64 * 40];

  const int tid = threadIdx.x;
  const int xrow0 = tid >> 2, xseg = tid & 3;
  const int ra = min(m0 + xrow0, ne - 1);
  const int rb = min(m0 + xrow0 + 64, ne - 1);
  const uint4* hpa = (const uint4*)(hbuf + (size_t)(off + ra) * HH);
  const uint4* hpb = (const uint4*)(hbuf + (size_t)(off + rb) * HH);
  const int wn_ = tid & 63, wkc = (tid >> 6) * 8;
  const float* w3p = w3 + (size_t)e * HH * DD + n0 + wn_;

  const int lane = tid & 63, wv = tid >> 6;
  const int wm = (wv >> 1) * 64, wn = (wv & 1) * 32;
  const int lr = lane & 15, lkb = (lane >> 4) * 8;

  f32x4 acc[4][2];
#pragma unroll
  for (int a = 0; a < 4; ++a)
#pragma unroll
    for (int b = 0; b < 2; ++b) acc[a][b] = f32x4{0.f, 0.f, 0.f, 0.f};

  for (int it = 0; it < HH / 32; ++it) {
    const int k0 = it * 32;
    const uint4 va = hpa[it * 4 + xseg];
    const uint4 vb = hpb[it * 4 + xseg];
    union { unsigned short u[8]; uint4 v; } p3;
#pragma unroll
    for (int j = 0; j < 8; ++j) p3.u[j] = f2bf(w3p[(size_t)(k0 + wkc + j) * DD]);
    __syncthreads();
    *(uint4*)&hs[xrow0 * 40 + xseg * 8] = va;
    *(uint4*)&hs[(xrow0 + 64) * 40 + xseg * 8] = vb;
    *(uint4*)&w3s[wn_ * 40 + wkc] = p3.v;
    __syncthreads();
    bf16x8 af[4], b3[2];
#pragma unroll
    for (int mf = 0; mf < 4; ++mf)
      af[mf] = *(const bf16x8*)&hs[(wm + mf * 16 + lr) * 40 + lkb];
#pragma unroll
    for (int nf = 0; nf < 2; ++nf)
      b3[nf] = *(const bf16x8*)&w3s[(wn + nf * 16 + lr) * 40 + lkb];
#pragma unroll
    for (int mf = 0; mf < 4; ++mf)
#pragma unroll
      for (int nf = 0; nf < 2; ++nf)
        acc[mf][nf] = __builtin_amdgcn_mfma_f32_16x16x32_bf16(af[mf], b3[nf], acc[mf][nf], 0, 0, 0);
  }
#pragma unroll
  for (int mf = 0; mf < 4; ++mf)
#pragma unroll
    for (int nf = 0; nf < 2; ++nf)
#pragma unroll
      for (int r = 0; r < 4; ++r) {
        const int rl = m0 + wm + mf * 16 + (lane >> 4) * 4 + r;
        if (rl < ne) {
          const int col = n0 + wn + nf * 16 + lr;
          ybuf[(size_t)(off + rl) * DD + col] = prow[off + rl] * acc[mf][nf][r];
        }
      }
}

// ---------------- combine: out[t] = y[row0(t)] + y[row1(t)] (already prob-scaled) ----------------
__global__ void combine_k(const float* __restrict__ y, const int* __restrict__ rowid,
                          float* __restrict__ out) {
  const int i = blockIdx.x * 256 + threadIdx.x;   // TOK*DD/4 threads
  const int t = i >> 8;                            // DD/4 = 256 float4 per row
  const float4 a = ((const float4*)(y + (size_t)rowid[2 * t] * DD))[i & 255];
  const float4 b = ((const float4*)(y + (size_t)rowid[2 * t + 1] * DD))[i & 255];
  float4 o; o.x = a.x + b.x; o.y = a.y + b.y; o.z = a.z + b.z; o.w = a.w + b.w;
  ((float4*)out)[i] = o;
}

// ---------------- workspace layout ----------------
#define WS_COUNTS 0
#define WS_OFFS 32
#define WS_CURS 64
#define WS_TOPI 128
#define WS_TOPP (WS_TOPI + TOK * 2 * 4)
#define WS_ROWID (WS_TOPP + TOK * 2 * 4)
#define WS_PERM (WS_ROWID + TOK * 2 * 4)
#define WS_PROW (WS_PERM + RTOT * 4)
#define WS_XB ((WS_PROW + RTOT * 4 + 255) & ~(size_t)255)
#define WS_H (WS_XB + (size_t)TOK * DD * 2)
#define WS_Y (WS_H + (size_t)RTOT * HH * 2)
// WS_END = WS_Y + RTOT*DD*4  ~= 72.2 MB

extern "C" void kernel_launch(void* const* d_in, const int* in_sizes, int n_in,
                              void* d_out, int out_size, void* d_ws, size_t ws_size,
                              hipStream_t stream) {
  const float* x = (const float*)d_in[0];
  const float* gw = (const float*)d_in[1];
  const float* w1 = (const float*)d_in[2];
  const float* w2 = (const float*)d_in[3];
  const float* w3 = (const float*)d_in[4];
  float* out = (float*)d_out;
  char* ws = (char*)d_ws;

  int* counts = (int*)(ws + WS_COUNTS);
  int* offsets = (int*)(ws + WS_OFFS);
  int* cursor = (int*)(ws + WS_CURS);
  int* topi = (int*)(ws + WS_TOPI);
  float* topp = (float*)(ws + WS_TOPP);
  int* rowid = (int*)(ws + WS_ROWID);
  int* perm = (int*)(ws + WS_PERM);
  float* prow = (float*)(ws + WS_PROW);
  unsigned short* Xb = (unsigned short*)(ws + WS_XB);
  unsigned short* hbuf = (unsigned short*)(ws + WS_H);
  float* ybuf = (float*)(ws + WS_Y);

  hipMemsetAsync(ws, 0, 128, stream);   // zero counts/offsets/cursor each launch
  router_k<<<TOK / 4, 256, 0, stream>>>(x, gw, topi, topp, counts);
  convert_k<<<TOK * DD / 4 / 256, 256, 0, stream>>>(x, Xb);
  scan_k<<<1, 64, 0, stream>>>(counts, offsets, cursor);
  scatter_k<<<TOK / 256, 256, 0, stream>>>(topi, topp, cursor, perm, prow, rowid);
  gemm1_k<<<dim3(HH / 64, RTOT / 128, NE), 256, 0, stream>>>(Xb, w1, w2, counts, offsets, perm, hbuf);
  gemm2_k<<<dim3(DD / 64, RTOT / 128, NE), 256, 0, stream>>>(hbuf, w3, counts, offsets, prow, ybuf);
  combine_k<<<TOK * DD / 4 / 256, 256, 0, stream>>>(ybuf, rowid, out);
}

// Round 2
// 384.978 us; speedup vs baseline: 1.0500x; 1.0500x over previous
//
#include <hip/hip_runtime.h>
#include <hip/hip_bf16.h>

// B=2,S=2048 -> T=4096 tokens, D=1024, H=2048, E=8, top_k=2
#define TOK 4096
#define DD 1024
#define HH 2048
#define NE 8
#define RTOT (TOK * 2)

typedef __attribute__((ext_vector_type(8))) short bf16x8;
typedef __attribute__((ext_vector_type(4))) float f32x4;

static __device__ __forceinline__ unsigned short f2bf(float f) {
  union { float f; unsigned int u; } v; v.f = f;
  unsigned int r = v.u + 0x7fffu + ((v.u >> 16) & 1u);
  return (unsigned short)(r >> 16);
}

// async global->LDS, 16B per lane; LDS dest = wave-uniform base + lane*16
static __device__ __forceinline__ void gload16(const unsigned short* g, unsigned short* l) {
  __builtin_amdgcn_global_load_lds(
      (const __attribute__((address_space(1))) unsigned int*)g,
      (__attribute__((address_space(3))) unsigned int*)l, 16, 0, 0);
}

// ---------------- router: fp32 gate scores, top-2, softmax over top-2 ----------------
__global__ void router_k(const float* __restrict__ x, const float* __restrict__ gw,
                         int* __restrict__ topi, float* __restrict__ topp,
                         int* __restrict__ counts) {
  const int lane = threadIdx.x & 63;
  const int t = blockIdx.x * 4 + (threadIdx.x >> 6);
  const float4* xr = (const float4*)(x + (size_t)t * DD);
  float acc[NE];
#pragma unroll
  for (int e = 0; e < NE; ++e) acc[e] = 0.f;
#pragma unroll
  for (int i = 0; i < 4; ++i) {
    const float4 xv = xr[i * 64 + lane];
#pragma unroll
    for (int e = 0; e < NE; ++e) {
      const float4 gv = ((const float4*)(gw + (size_t)e * DD))[i * 64 + lane];
      acc[e] += xv.x * gv.x + xv.y * gv.y + xv.z * gv.z + xv.w * gv.w;
    }
  }
#pragma unroll
  for (int e = 0; e < NE; ++e)
#pragma unroll
    for (int s = 32; s > 0; s >>= 1) acc[e] += __shfl_xor(acc[e], s, 64);
  if (lane == 0) {
    int i0 = 0; float v0 = acc[0];
#pragma unroll
    for (int e = 1; e < NE; ++e) if (acc[e] > v0) { v0 = acc[e]; i0 = e; }
    int i1 = -1; float v1 = -1e30f;
#pragma unroll
    for (int e = 0; e < NE; ++e) if (e != i0 && acc[e] > v1) { v1 = acc[e]; i1 = e; }
    const float ex = __expf(v1 - v0);
    const float inv = 1.f / (1.f + ex);
    topi[t * 2] = i0; topi[t * 2 + 1] = i1;
    topp[t * 2] = inv; topp[t * 2 + 1] = ex * inv;
    atomicAdd(&counts[i0], 1); atomicAdd(&counts[i1], 1);
  }
}

// ---------------- x fp32 -> bf16 ----------------
__global__ void convert_k(const float* __restrict__ x, unsigned short* __restrict__ xb) {
  const int i = blockIdx.x * 256 + threadIdx.x;
  const float4 v = ((const float4*)x)[i];
  ushort4 o;
  o.x = f2bf(v.x); o.y = f2bf(v.y); o.z = f2bf(v.z); o.w = f2bf(v.w);
  ((ushort4*)xb)[i] = o;
}

// ---------------- weight transpose+convert: in fp32 [R][C] -> out bf16 [C][R] ----------------
// z = mat*8 + e; mat0: w1 (R=DD,C=HH), mat1: w2, mat2: w3 (R=HH,C=DD). 64x64 tiles.
__global__ __launch_bounds__(256) void transpose_k(
    const float* __restrict__ w1, const float* __restrict__ w2, const float* __restrict__ w3,
    unsigned short* __restrict__ w1t, unsigned short* __restrict__ w2t,
    unsigned short* __restrict__ w3t) {
  const int z = blockIdx.y;
  const int mat = z >> 3, e = z & 7;
  const float* in; unsigned short* out; int R, C;
  if (mat == 0)      { in = w1 + (size_t)e * DD * HH; out = w1t + (size_t)e * HH * DD; R = DD; C = HH; }
  else if (mat == 1) { in = w2 + (size_t)e * DD * HH; out = w2t + (size_t)e * HH * DD; R = DD; C = HH; }
  else               { in = w3 + (size_t)e * HH * DD; out = w3t + (size_t)e * DD * HH; R = HH; C = DD; }
  const int ctiles = C >> 6;
  const int tc = blockIdx.x % ctiles, tr = blockIdx.x / ctiles;
  const int c0 = tc * 64, r0 = tr * 64;
  __shared__ unsigned short t[64 * 72];
  const int lane = threadIdx.x & 63, wv = threadIdx.x >> 6;
#pragma unroll
  for (int p = 0; p < 4; ++p) {
    const int rb = (wv * 4 + p) * 4;
    ushort4 o;
    o.x = f2bf(in[(size_t)(r0 + rb + 0) * C + c0 + lane]);
    o.y = f2bf(in[(size_t)(r0 + rb + 1) * C + c0 + lane]);
    o.z = f2bf(in[(size_t)(r0 + rb + 2) * C + c0 + lane]);
    o.w = f2bf(in[(size_t)(r0 + rb + 3) * C + c0 + lane]);
    *(ushort4*)&t[lane * 72 + rb] = o;       // t[c][r]
  }
  __syncthreads();
#pragma unroll
  for (int q = 0; q < 2; ++q) {
    const int idx = q * 256 + threadIdx.x;
    const int crow = idx >> 3, seg = idx & 7;
    const uint4 v = *(const uint4*)&t[crow * 72 + seg * 8];
    *(uint4*)&out[(size_t)(c0 + crow) * R + r0 + seg * 8] = v;
  }
}

// ---------------- tiny exclusive scan ----------------
__global__ void scan_k(const int* __restrict__ counts, int* __restrict__ offsets,
                       int* __restrict__ cursor) {
  if (threadIdx.x == 0) {
    int s = 0;
    for (int e = 0; e < NE; ++e) { offsets[e] = s; cursor[e] = s; s += counts[e]; }
  }
}

// ---------------- scatter tokens into per-expert row lists ----------------
__global__ void scatter_k(const int* __restrict__ topi, const float* __restrict__ topp,
                          int* __restrict__ cursor, int* __restrict__ perm,
                          float* __restrict__ prow, int* __restrict__ rowid) {
  const int t = blockIdx.x * 256 + threadIdx.x;
#pragma unroll
  for (int k = 0; k < 2; ++k) {
    const int e = topi[t * 2 + k];
    const int pos = atomicAdd(&cursor[e], 1);
    perm[pos] = t;
    prow[pos] = topp[t * 2 + k];
    rowid[t * 2 + k] = pos;
  }
}

// ---------------- GEMM1: gathered X @ (w1t,w2t) -> h = silu(g)*u (bf16) ----------------
// BM=128, BN=64, BK=64; 4 waves (2m x 2n); global_load_lds staging with XOR-swizzled slots.
__global__ __launch_bounds__(256) void gemm1_k(
    const unsigned short* __restrict__ Xb, const unsigned short* __restrict__ w1t,
    const unsigned short* __restrict__ w2t, const int* __restrict__ counts,
    const int* __restrict__ offsets, const int* __restrict__ perm,
    unsigned short* __restrict__ hbuf) {
  const int e = blockIdx.z;
  const int ne = counts[e];
  const int m0 = blockIdx.y * 128;
  if (m0 >= ne) return;
  const int off = offsets[e];
  const int n0 = blockIdx.x * 64;

  __shared__ unsigned short xs[128 * 64];   // 16KB, row stride 128B
  __shared__ unsigned short w1s[64 * 64];   // 8KB
  __shared__ unsigned short w2s[64 * 64];   // 8KB

  const int tid = threadIdx.x;
  const int lane = tid & 63, wv = tid >> 6;
  const int lrow8 = lane >> 3;                       // row within an 8-row issue
  const int schunk = ((lane & 7) ^ lrow8) * 8;       // pre-swizzled source chunk (shorts)

  const unsigned short* pA[4]; unsigned short* dA[4];
#pragma unroll
  for (int q = 0; q < 4; ++q) {
    const int row = wv * 32 + q * 8 + lrow8;
    const int g = perm[off + min(m0 + row, ne - 1)];
    pA[q] = Xb + (size_t)g * DD + schunk;
    dA[q] = &xs[(wv * 32 + q * 8) * 64];
  }
  const unsigned short* pB1[2]; const unsigned short* pB2[2];
  unsigned short* dB1[2]; unsigned short* dB2[2];
#pragma unroll
  for (int q = 0; q < 2; ++q) {
    const int row = wv * 16 + q * 8 + lrow8;
    pB1[q] = w1t + ((size_t)e * HH + n0 + row) * DD + schunk;
    pB2[q] = w2t + ((size_t)e * HH + n0 + row) * DD + schunk;
    dB1[q] = &w1s[(wv * 16 + q * 8) * 64];
    dB2[q] = &w2s[(wv * 16 + q * 8) * 64];
  }

  const int wm = (wv >> 1) * 64, wn = (wv & 1) * 32;
  const int lr = lane & 15, kc = lane >> 4;
  const int s0 = (kc ^ (lr & 7)) * 8;          // ds_read slot, kk=0
  const int s1 = ((kc + 4) ^ (lr & 7)) * 8;    // kk=1

  f32x4 accG[4][2], accU[4][2];
#pragma unroll
  for (int a = 0; a < 4; ++a)
#pragma unroll
    for (int b = 0; b < 2; ++b) {
      accG[a][b] = f32x4{0.f, 0.f, 0.f, 0.f};
      accU[a][b] = f32x4{0.f, 0.f, 0.f, 0.f};
    }

  for (int it = 0; it < DD / 64; ++it) {
#pragma unroll
    for (int q = 0; q < 4; ++q) { gload16(pA[q], dA[q]); pA[q] += 64; }
#pragma unroll
    for (int q = 0; q < 2; ++q) {
      gload16(pB1[q], dB1[q]); pB1[q] += 64;
      gload16(pB2[q], dB2[q]); pB2[q] += 64;
    }
    __syncthreads();   // drains vmcnt -> tile ready
#pragma unroll
    for (int kk = 0; kk < 2; ++kk) {
      const int sk = kk ? s1 : s0;
      bf16x8 af[4], bg[2], bu[2];
#pragma unroll
      for (int mf = 0; mf < 4; ++mf)
        af[mf] = *(const bf16x8*)&xs[(wm + mf * 16 + lr) * 64 + sk];
#pragma unroll
      for (int nf = 0; nf < 2; ++nf) {
        bg[nf] = *(const bf16x8*)&w1s[(wn + nf * 16 + lr) * 64 + sk];
        bu[nf] = *(const bf16x8*)&w2s[(wn + nf * 16 + lr) * 64 + sk];
      }
#pragma unroll
      for (int mf = 0; mf < 4; ++mf)
#pragma unroll
        for (int nf = 0; nf < 2; ++nf) {
          accG[mf][nf] = __builtin_amdgcn_mfma_f32_16x16x32_bf16(af[mf], bg[nf], accG[mf][nf], 0, 0, 0);
          accU[mf][nf] = __builtin_amdgcn_mfma_f32_16x16x32_bf16(af[mf], bu[nf], accU[mf][nf], 0, 0, 0);
        }
    }
    __syncthreads();   // reads done before next overwrite
  }
#pragma unroll
  for (int mf = 0; mf < 4; ++mf)
#pragma unroll
    for (int nf = 0; nf < 2; ++nf)
#pragma unroll
      for (int r = 0; r < 4; ++r) {
        const int rl = m0 + wm + mf * 16 + (lane >> 4) * 4 + r;
        if (rl < ne) {
          const int col = n0 + wn + nf * 16 + lr;
          const float g = accG[mf][nf][r], u = accU[mf][nf][r];
          const float hv = g / (1.f + __expf(-g)) * u;
          hbuf[(size_t)(off + rl) * HH + col] = f2bf(hv);
        }
      }
}

// ---------------- GEMM2: h @ w3t (scaled by prob) -> y fp32 ----------------
// BM=128, BN=64, BK=64; K=HH.
__global__ __launch_bounds__(256) void gemm2_k(
    const unsigned short* __restrict__ hbuf, const unsigned short* __restrict__ w3t,
    const int* __restrict__ counts, const int* __restrict__ offsets,
    const float* __restrict__ prow, float* __restrict__ ybuf) {
  const int e = blockIdx.z;
  const int ne = counts[e];
  const int m0 = blockIdx.y * 128;
  if (m0 >= ne) return;
  const int off = offsets[e];
  const int n0 = blockIdx.x * 64;

  __shared__ unsigned short hs[128 * 64];
  __shared__ unsigned short w3s[64 * 64];

  const int tid = threadIdx.x;
  const int lane = tid & 63, wv = tid >> 6;
  const int lrow8 = lane >> 3;
  const int schunk = ((lane & 7) ^ lrow8) * 8;

  const unsigned short* pA[4]; unsigned short* dA[4];
#pragma unroll
  for (int q = 0; q < 4; ++q) {
    const int row = wv * 32 + q * 8 + lrow8;
    pA[q] = hbuf + (size_t)(off + min(m0 + row, ne - 1)) * HH + schunk;
    dA[q] = &hs[(wv * 32 + q * 8) * 64];
  }
  const unsigned short* pB[2]; unsigned short* dB[2];
#pragma unroll
  for (int q = 0; q < 2; ++q) {
    const int row = wv * 16 + q * 8 + lrow8;
    pB[q] = w3t + ((size_t)e * DD + n0 + row) * HH + schunk;
    dB[q] = &w3s[(wv * 16 + q * 8) * 64];
  }

  const int wm = (wv >> 1) * 64, wn = (wv & 1) * 32;
  const int lr = lane & 15, kc = lane >> 4;
  const int s0 = (kc ^ (lr & 7)) * 8;
  const int s1 = ((kc + 4) ^ (lr & 7)) * 8;

  f32x4 acc[4][2];
#pragma unroll
  for (int a = 0; a < 4; ++a)
#pragma unroll
    for (int b = 0; b < 2; ++b) acc[a][b] = f32x4{0.f, 0.f, 0.f, 0.f};

  for (int it = 0; it < HH / 64; ++it) {
#pragma unroll
    for (int q = 0; q < 4; ++q) { gload16(pA[q], dA[q]); pA[q] += 64; }
#pragma unroll
    for (int q = 0; q < 2; ++q) { gload16(pB[q], dB[q]); pB[q] += 64; }
    __syncthreads();
#pragma unroll
    for (int kk = 0; kk < 2; ++kk) {
      const int sk = kk ? s1 : s0;
      bf16x8 af[4], b3[2];
#pragma unroll
      for (int mf = 0; mf < 4; ++mf)
        af[mf] = *(const bf16x8*)&hs[(wm + mf * 16 + lr) * 64 + sk];
#pragma unroll
      for (int nf = 0; nf < 2; ++nf)
        b3[nf] = *(const bf16x8*)&w3s[(wn + nf * 16 + lr) * 64 + sk];
#pragma unroll
      for (int mf = 0; mf < 4; ++mf)
#pragma unroll
        for (int nf = 0; nf < 2; ++nf)
          acc[mf][nf] = __builtin_amdgcn_mfma_f32_16x16x32_bf16(af[mf], b3[nf], acc[mf][nf], 0, 0, 0);
    }
    __syncthreads();
  }
#pragma unroll
  for (int mf = 0; mf < 4; ++mf)
#pragma unroll
    for (int nf = 0; nf < 2; ++nf)
#pragma unroll
      for (int r = 0; r < 4; ++r) {
        const int rl = m0 + wm + mf * 16 + (lane >> 4) * 4 + r;
        if (rl < ne) {
          const int col = n0 + wn + nf * 16 + lr;
          ybuf[(size_t)(off + rl) * DD + col] = prow[off + rl] * acc[mf][nf][r];
        }
      }
}

// ---------------- combine: out[t] = y[row0(t)] + y[row1(t)] ----------------
__global__ void combine_k(const float* __restrict__ y, const int* __restrict__ rowid,
                          float* __restrict__ out) {
  const int i = blockIdx.x * 256 + threadIdx.x;
  const int t = i >> 8;
  const float4 a = ((const float4*)(y + (size_t)rowid[2 * t] * DD))[i & 255];
  const float4 b = ((const float4*)(y + (size_t)rowid[2 * t + 1] * DD))[i & 255];
  float4 o; o.x = a.x + b.x; o.y = a.y + b.y; o.z = a.z + b.z; o.w = a.w + b.w;
  ((float4*)out)[i] = o;
}

// ---------------- workspace layout ----------------
#define WS_COUNTS 0
#define WS_OFFS 32
#define WS_CURS 64
#define WS_TOPI 128
#define WS_TOPP (WS_TOPI + TOK * 2 * 4)
#define WS_ROWID (WS_TOPP + TOK * 2 * 4)
#define WS_PERM (WS_ROWID + TOK * 2 * 4)
#define WS_PROW (WS_PERM + RTOT * 4)
#define WS_XB ((WS_PROW + RTOT * 4 + 255) & ~(size_t)255)
#define WS_H (WS_XB + (size_t)TOK * DD * 2)
#define WS_W1T (WS_H + (size_t)RTOT * HH * 2)
#define WS_W2T (WS_W1T + (size_t)NE * HH * DD * 2)
#define WS_W3T (WS_W2T + (size_t)NE * HH * DD * 2)
#define WS_Y WS_W1T   // ybuf (32MB) aliases w1t (dead after gemm1)
// end = WS_W3T + NE*HH*DD*2 ~= 141 MB

extern "C" void kernel_launch(void* const* d_in, const int* in_sizes, int n_in,
                              void* d_out, int out_size, void* d_ws, size_t ws_size,
                              hipStream_t stream) {
  const float* x = (const float*)d_in[0];
  const float* gw = (const float*)d_in[1];
  const float* w1 = (const float*)d_in[2];
  const float* w2 = (const float*)d_in[3];
  const float* w3 = (const float*)d_in[4];
  float* out = (float*)d_out;
  char* ws = (char*)d_ws;

  int* counts = (int*)(ws + WS_COUNTS);
  int* offsets = (int*)(ws + WS_OFFS);
  int* cursor = (int*)(ws + WS_CURS);
  int* topi = (int*)(ws + WS_TOPI);
  float* topp = (float*)(ws + WS_TOPP);
  int* rowid = (int*)(ws + WS_ROWID);
  int* perm = (int*)(ws + WS_PERM);
  float* prow = (float*)(ws + WS_PROW);
  unsigned short* Xb = (unsigned short*)(ws + WS_XB);
  unsigned short* hbuf = (unsigned short*)(ws + WS_H);
  unsigned short* w1t = (unsigned short*)(ws + WS_W1T);
  unsigned short* w2t = (unsigned short*)(ws + WS_W2T);
  unsigned short* w3t = (unsigned short*)(ws + WS_W3T);
  float* ybuf = (float*)(ws + WS_Y);

  hipMemsetAsync(ws, 0, 128, stream);
  transpose_k<<<dim3(512, 24), 256, 0, stream>>>(w1, w2, w3, w1t, w2t, w3t);
  router_k<<<TOK / 4, 256, 0, stream>>>(x, gw, topi, topp, counts);
  convert_k<<<TOK * DD / 4 / 256, 256, 0, stream>>>(x, Xb);
  scan_k<<<1, 64, 0, stream>>>(counts, offsets, cursor);
  scatter_k<<<TOK / 256, 256, 0, stream>>>(topi, topp, cursor, perm, prow, rowid);
  gemm1_k<<<dim3(HH / 64, RTOT / 128, NE), 256, 0, stream>>>(Xb, w1t, w2t, counts, offsets, perm, hbuf);
  gemm2_k<<<dim3(DD / 64, RTOT / 128, NE), 256, 0, stream>>>(hbuf, w3t, counts, offsets, prow, ybuf);
  combine_k<<<TOK * DD / 4 / 256, 256, 0, stream>>>(ybuf, rowid, out);
}